// Round 6
// baseline (25710.437 us; speedup 1.0000x reference)
//
#include <hip/hip_runtime.h>

typedef unsigned int u32;

#define NB      2048
#define CEM_NS  1000
#define CEM_NE  100
#define CEM_NI  10
#define NSF     1000
#define HD      128
#define BLOCK   256

struct KeyPack { u32 kk[2 * CEM_NI]; };

__host__ __device__ inline u32 rotl32(u32 v, int r) { return (v << r) | (v >> (32 - r)); }

// Exact JAX threefry2x32 (rotations [13,15,26,6]/[17,29,16,24], 5 groups, key injections +1..+5)
__host__ __device__ inline void threefry2x32(u32 k0, u32 k1, u32 x0, u32 x1, u32* o0, u32* o1) {
  u32 k2 = k0 ^ k1 ^ 0x1BD11BDAu;
  x0 += k0; x1 += k1;
#define TFR(r) { x0 += x1; x1 = rotl32(x1, r); x1 ^= x0; }
  TFR(13) TFR(15) TFR(26) TFR(6)
  x0 += k1; x1 += k2 + 1u;
  TFR(17) TFR(29) TFR(16) TFR(24)
  x0 += k2; x1 += k0 + 2u;
  TFR(13) TFR(15) TFR(26) TFR(6)
  x0 += k0; x1 += k1 + 3u;
  TFR(17) TFR(29) TFR(16) TFR(24)
  x0 += k1; x1 += k2 + 4u;
  TFR(13) TFR(15) TFR(26) TFR(6)
  x0 += k2; x1 += k0 + 5u;
#undef TFR
  *o0 = x0; *o1 = x1;
}

// XLA EmitLog1p: |a|<1e-4 ? a*((-0.5*a)+1) : log(a+1). log -> ocml log (same as HIP logf).
__device__ __forceinline__ float log1p_xla(float a) {
#pragma clang fp contract(off)
  float for_large = logf(a + 1.0f);
  float for_small = ((-0.5f * a) + 1.0f) * a;
  return (fabsf(a) < 1e-4f) ? for_small : for_large;
}

// XLA/chlo erf_inv f32 decomposition (Giles), unfused mul/add like the HLO expansion.
__device__ __forceinline__ float jax_erfinv(float u) {
#pragma clang fp contract(off)
  float xx = u * u;
  float w = -log1p_xla(-xx);
  float ws = w - 2.5f;
  float p =  2.81022636e-08f;
  p =  3.43273939e-07f + p * ws;
  p = -3.5233877e-06f  + p * ws;
  p = -4.39150654e-06f + p * ws;
  p =  0.00021858087f  + p * ws;
  p = -0.00125372503f  + p * ws;
  p = -0.00417768164f  + p * ws;
  p =  0.246640727f    + p * ws;
  p =  1.50140941f     + p * ws;
  float wb = sqrtf(w) - 3.0f;
  float q = -0.000200214257f;
  q =  0.000100950558f + q * wb;
  q =  0.00134934322f  + q * wb;
  q = -0.00367342844f  + q * wb;
  q =  0.00573950773f  + q * wb;
  q = -0.0076224613f   + q * wb;
  q =  0.00943887047f  + q * wb;
  q =  1.00167406f     + q * wb;
  q =  2.83297682f     + q * wb;
  float pv = (w < 5.0f) ? p : q;
  return pv * u;
}

// PARTITIONABLE threefry random bits (JAX >= 0.4.30 default):
// bits[n] = o0 ^ o1 of threefry(key, (hi32(n), lo32(n))); sizes < 2^32 so hi = 0.
// Then f = bitcast(bits>>9|0x3f800000)-1 in [0,1); u = max(lo, f*2+lo); normal = sqrt2*erfinv(u).
__device__ __forceinline__ float jax_normal_at(u32 k0, u32 k1, u32 n) {
  u32 o0, o1;
  threefry2x32(k0, k1, 0u, n, &o0, &o1);
  u32 bits = o0 ^ o1;
  float res;
  {
#pragma clang fp contract(off)
    float f = __uint_as_float((bits >> 9) | 0x3f800000u) - 1.0f;
    const float lo = -0.99999994f;       // nextafter(-1,0); (1-lo) rounds to exactly 2.0f
    float uu = f * 2.0f + lo;
    uu = fmaxf(lo, uu);
    res = 1.41421354f * jax_erfinv(uu);  // f32(sqrt(2)) = 0x3FB504F3
  }
  return res;
}

// XLA EmitFastTanh f32: clamp +-7.90531110763549805, rational poly, |x|<4e-4 -> x. Unfused.
__device__ __forceinline__ float tanh_xla(float x) {
#pragma clang fp contract(off)
  float ax = fabsf(x);
  float cx = fminf(fmaxf(x, -7.90531110763549805f), 7.90531110763549805f);
  float x2 = cx * cx;
  float pn = -2.76076847742355e-16f;
  pn =  2.00018790482477e-13f + pn * x2;
  pn = -8.60467152213735e-11f + pn * x2;
  pn =  5.12229709037114e-08f + pn * x2;
  pn =  1.48572235717979e-05f + pn * x2;
  pn =  6.37261928875436e-04f + pn * x2;
  pn =  4.89352455891786e-03f + pn * x2;
  float numer = cx * pn;
  float pd =  1.19825839466702e-06f;
  pd =  1.18534705686654e-04f + pd * x2;
  pd =  2.26843463243900e-03f + pd * x2;
  pd =  4.89352518554385e-03f + pd * x2;
  float r = numer / pd;   // IEEE f32 divide (no fast-math in harness flags)
  return (ax < 0.0004f) ? x : r;
}

__global__ void transpose_kernel(const float* __restrict__ W2, float* __restrict__ W2T) {
  const int idx = blockIdx.x * BLOCK + threadIdx.x;   // idx = j*128 + k
  const int j = idx >> 7;
  const int k = idx & (HD - 1);
  W2T[idx] = W2[k * HD + j];
}

__global__ void __launch_bounds__(BLOCK, 2) cem_kernel(
    const float* __restrict__ x_in, const float* __restrict__ W1,
    const float* __restrict__ b1, const float* __restrict__ W2T,
    const float* __restrict__ b2, const float* __restrict__ W3,
    const float* __restrict__ b3, float* __restrict__ yhat_out,
    float* __restrict__ scale_out, KeyPack keys) {
  __shared__ float sF[CEM_NS];
  __shared__ float sY[CEM_NS];
  __shared__ __align__(16) float sA[HD];
  __shared__ u32 sHist[256];
  __shared__ float sRed[6];
  __shared__ u32 sU[3];

  const int tid = threadIdx.x;
  const int b = blockIdx.x;
  const float xb = x_in[b];
  if (tid < HD) {
#pragma clang fp contract(off)
    sA[tid] = xb * W1[tid];          // x * W1[0][k]; fma(x,w,0) == rounded product
  }
  __syncthreads();

  const float b3v = b3[0];
  float mu = 0.0f;
  float sigma = 10.0f;

  for (int t = 0; t < CEM_NI; ++t) {
    const u32 kk0 = keys.kk[2 * t];
    const u32 kk1 = keys.kk[2 * t + 1];

    // ---- evaluate 1000 candidates: lane = candidate; weights via wave-uniform float4 loads ----
    for (int i = tid; i < CEM_NS; i += BLOCK) {
      const u32 n = (u32)(b * CEM_NS + i);   // flat index into (NB, CEM_NS) row-major
      const float eps = jax_normal_at(kk0, kk1, n);
      float Yc;
      {
#pragma clang fp contract(off)
        Yc = mu + sigma * eps;       // mu + sigma*eps, unfused like XLA broadcast ops
      }
      // ---- layer 1: 2 -> 128, float4-ized over k ----
      float h1[HD];
#pragma unroll
      for (int kc = 0; kc < HD / 4; ++kc) {
        const float4 w1v = *(const float4*)(W1 + HD + 4 * kc);
        const float4 b1v = *(const float4*)(b1 + 4 * kc);
        const float4 sav = *(const float4*)(&sA[4 * kc]);
        float p0, p1, p2, p3;
        {
#pragma clang fp contract(off)
          p0 = fmaf(Yc, w1v.x, sav.x) + b1v.x;   // fma(y,w1,round(x*w0)) then separate +b1
          p1 = fmaf(Yc, w1v.y, sav.y) + b1v.y;
          p2 = fmaf(Yc, w1v.z, sav.z) + b1v.z;
          p3 = fmaf(Yc, w1v.w, sav.w) + b1v.w;
        }
        h1[4 * kc + 0] = tanh_xla(p0);
        h1[4 * kc + 1] = tanh_xla(p1);
        h1[4 * kc + 2] = tanh_xla(p2);
        h1[4 * kc + 3] = tanh_xla(p3);
      }
      // ---- layer 2 (128x128) + layer 3, 4 output rows per j-block for ILP ----
      float E = 0.0f;
#pragma unroll 1
      for (int j = 0; j < HD; j += 4) {
        const float4* __restrict__ wr0 = (const float4*)(W2T + (j + 0) * HD);
        const float4* __restrict__ wr1 = (const float4*)(W2T + (j + 1) * HD);
        const float4* __restrict__ wr2 = (const float4*)(W2T + (j + 2) * HD);
        const float4* __restrict__ wr3 = (const float4*)(W2T + (j + 3) * HD);
        float a0 = 0.0f, a1 = 0.0f, a2 = 0.0f, a3 = 0.0f;
#pragma unroll
        for (int kc = 0; kc < HD / 4; ++kc) {
          const float4 w0 = wr0[kc];
          const float4 w1 = wr1[kc];
          const float4 w2 = wr2[kc];
          const float4 w3 = wr3[kc];
          const float h0 = h1[4 * kc + 0], hh1 = h1[4 * kc + 1];
          const float h2 = h1[4 * kc + 2], h3 = h1[4 * kc + 3];
          a0 = fmaf(h0, w0.x, a0); a0 = fmaf(hh1, w0.y, a0);
          a0 = fmaf(h2, w0.z, a0); a0 = fmaf(h3, w0.w, a0);
          a1 = fmaf(h0, w1.x, a1); a1 = fmaf(hh1, w1.y, a1);
          a1 = fmaf(h2, w1.z, a1); a1 = fmaf(h3, w1.w, a1);
          a2 = fmaf(h0, w2.x, a2); a2 = fmaf(hh1, w2.y, a2);
          a2 = fmaf(h2, w2.z, a2); a2 = fmaf(h3, w2.w, a2);
          a3 = fmaf(h0, w3.x, a3); a3 = fmaf(hh1, w3.y, a3);
          a3 = fmaf(h2, w3.z, a3); a3 = fmaf(h3, w3.w, a3);
        }
        const float4 b2v = *(const float4*)(b2 + j);
        const float4 w3v = *(const float4*)(W3 + j);
        float h20, h21, h22, h23;
        {
#pragma clang fp contract(off)
          h20 = tanh_xla(a0 + b2v.x);
          h21 = tanh_xla(a1 + b2v.y);
          h22 = tanh_xla(a2 + b2v.z);
          h23 = tanh_xla(a3 + b2v.w);
        }
        E = fmaf(h20, w3v.x, E);
        E = fmaf(h21, w3v.y, E);
        E = fmaf(h22, w3v.z, E);
        E = fmaf(h23, w3v.w, E);
      }
      float fv;
      {
#pragma clang fp contract(off)
        float Ef = E + b3v;
        fv = Ef * Ef;
      }
      sF[i] = fv;
      sY[i] = Yc;
    }
    __syncthreads();

    // ---- exact radix select: bits of 100th-smallest f (all f >= +0, uint order = float order) ----
    u32 prefix = 0u, need = CEM_NE, cntEq = 0u;
    for (int pass = 0; pass < 4; ++pass) {
      const int shift = 24 - 8 * pass;
      sHist[tid] = 0u;
      __syncthreads();
      for (int i = tid; i < CEM_NS; i += BLOCK) {
        const u32 bits = __float_as_uint(sF[i]);
        const bool match = (pass == 0) ? true : ((bits >> (shift + 8)) == prefix);
        if (match) atomicAdd(&sHist[(bits >> shift) & 255u], 1u);
      }
      __syncthreads();
      if (tid == 0) {
        u32 acc = 0u, d = 0u;
        for (d = 0u; d < 256u; ++d) {
          const u32 c = sHist[d];
          if (acc + c >= need) break;
          acc += c;
        }
        sU[0] = (prefix << 8) | d;
        sU[1] = need - acc;
        sU[2] = sHist[d];
      }
      __syncthreads();
      prefix = sU[0]; need = sU[1]; cntEq = sU[2];
    }
    const u32 Tbits = prefix;   // bit pattern of rank-100 (1-based) smallest f
    const u32 m = need;         // how many ==T to take (lowest index first, = top_k ties)

    // ---- elite mean ----
    float sumY = 0.0f;
    u32 eliteMask = 0u;
    for (int i = tid; i < CEM_NS; i += BLOCK) {
      const u32 bits = __float_as_uint(sF[i]);
      bool el = (bits < Tbits);
      if (!el && bits == Tbits) {
        if (cntEq == m) {
          el = true;                       // all ties included (common case)
        } else {
          u32 rr = 0u;
          for (int j2 = 0; j2 < i; ++j2) rr += (__float_as_uint(sF[j2]) == Tbits) ? 1u : 0u;
          el = (rr < m);
        }
      }
      if (el) { sumY += sY[i]; eliteMask |= (1u << (((u32)i) >> 8)); }
    }
    float wsum = sumY;
    for (int off = 1; off < 64; off <<= 1) wsum += __shfl_xor(wsum, off, 64);
    if ((tid & 63) == 0) sRed[tid >> 6] = wsum;
    __syncthreads();
    if (tid == 0) sRed[4] = ((sRed[0] + sRed[1]) + sRed[2]) + sRed[3];
    __syncthreads();
    const float mu_n = sRed[4] / 100.0f;

    // ---- elite variance ----
    float ssq = 0.0f;
    for (int i = tid; i < CEM_NS; i += BLOCK) {
      if (eliteMask & (1u << (((u32)i) >> 8))) {
#pragma clang fp contract(off)
        const float dd = sY[i] - mu_n;
        ssq += dd * dd;
      }
    }
    float wss = ssq;
    for (int off = 1; off < 64; off <<= 1) wss += __shfl_xor(wss, off, 64);
    if ((tid & 63) == 0) sRed[tid >> 6] = wss;
    __syncthreads();
    if (tid == 0) sRed[4] = ((sRed[0] + sRed[1]) + sRed[2]) + sRed[3];
    __syncthreads();
    const float var_n = sRed[4] / 100.0f;

    mu = mu_n;
    sigma = sqrtf(var_n);
    __syncthreads();
  }

  if (tid == 0) {
    yhat_out[b] = mu;
    {
#pragma clang fp contract(off)
      const float cov = sigma * sigma;                     // square(sigma)
      const float covc = fminf(fmaxf(cov, 1e-3f), 100.0f); // clip(cov/1.0, 1e-3, 100)
      scale_out[b] = sqrtf(covc);
    }
  }
}

__global__ void sample_kernel(const float* __restrict__ yhat,
                              const float* __restrict__ scale,
                              float* __restrict__ out, u32 k0, u32 k1) {
  const int nidx = blockIdx.x * BLOCK + threadIdx.x;  // grid exact: 8000*256 = 2,048,000
  const float eps = jax_normal_at(k0, k1, (u32)nidx); // flat index into (NS, NB) row-major
  const int bb = nidx & (NB - 1);
  {
#pragma clang fp contract(off)
    out[nidx] = yhat[bb] + scale[bb] * eps;
  }
}

extern "C" void kernel_launch(void* const* d_in, const int* in_sizes, int n_in,
                              void* d_out, int out_size, void* d_ws, size_t ws_size,
                              hipStream_t stream) {
  (void)in_sizes; (void)n_in; (void)out_size; (void)ws_size;
  const float* x  = (const float*)d_in[0];
  const float* W1 = (const float*)d_in[1];
  const float* b1 = (const float*)d_in[2];
  const float* W2 = (const float*)d_in[3];
  const float* b2 = (const float*)d_in[4];
  const float* W3 = (const float*)d_in[5];
  const float* b3 = (const float*)d_in[6];
  float* yhat  = (float*)d_out;               // out[0..2047]
  float* ysamp = yhat + NB;                   // out[2048..2050047], (s,b) row-major
  float* W2T   = (float*)d_ws;                                  // 64 KiB
  float* scale = (float*)((char*)d_ws + (size_t)HD * HD * 4);   // 8 KiB

  // ---- host-side exact JAX key derivation, PARTITIONABLE (fold-like) semantics ----
  // key(42) = (0,42).
  // split(key,2) fold-like: key_i = (o0,o1) of threefry(key, (0, i)) for i = 0,1.
  u32 kc0, kc1, ks0, ks1;
  threefry2x32(0u, 42u, 0u, 0u, &kc0, &kc1);   // k_cem  = keys[0]
  threefry2x32(0u, 42u, 0u, 1u, &ks0, &ks1);   // k_samp = keys[1]
  // split(k_cem,10) fold-like: key_t = (o0,o1) of threefry(k_cem, (0, t)) for t = 0..9.
  KeyPack kp;
  for (u32 t = 0; t < CEM_NI; ++t)
    threefry2x32(kc0, kc1, 0u, t, &kp.kk[2 * t], &kp.kk[2 * t + 1]);

  transpose_kernel<<<(HD * HD) / BLOCK, BLOCK, 0, stream>>>(W2, W2T);
  cem_kernel<<<NB, BLOCK, 0, stream>>>(x, W1, b1, W2T, b2, W3, b3, yhat, scale, kp);
  sample_kernel<<<(NSF * NB) / BLOCK, BLOCK, 0, stream>>>(yhat, scale, ysamp, ks0, ks1);
}